// Round 11
// baseline (136.295 us; speedup 1.0000x reference)
//
#include <hip/hip_runtime.h>
#include <hip/hip_bf16.h>

// BPTT diagonal RNN: u = X @ B^T (bf16 MFMA), then chunked diagonal scan.
// R11: gemm8p3 = R8's proven gemm8p2 with the 2 mid-iteration barriers removed
// (1 s_barrier per K-tile; ring/vmcnt discipline unchanged -> race-free).
// cvt uses nontemporal load/store. Scans + fallback unchanged.

#define TDIM 8192
#define HDIM 2048
#define BM 256
#define BN 256
#define BK 32
#define NT (HDIM / BK)         // 64 K-tiles
#define ASLOT 8192             // shorts per A slot (256*32)
#define BSLOT 8192
#define LCH 64                 // scan chunk length
#define GCH (TDIM / LCH)       // 128 chunks

#define XBF_BYTES (TDIM * HDIM * 2)
#define BBF_BYTES (HDIM * HDIM * 2)
#define E_BYTES   (GCH * HDIM * 4)
#define WS_NEED   ((size_t)XBF_BYTES + BBF_BYTES + E_BYTES)

typedef float f32x4 __attribute__((ext_vector_type(4)));
typedef short s16x4 __attribute__((ext_vector_type(4)));
typedef short s16x8 __attribute__((ext_vector_type(8)));

static __device__ __forceinline__ short f2bf(float f) {
  __bf16 b = (__bf16)f;
  return __builtin_bit_cast(short, b);
}

#define SB()   asm volatile("s_barrier" ::: "memory")
#define VMW(n) asm volatile("s_waitcnt vmcnt(" #n ")" ::: "memory")
#define GL(gp, lp)                                                            \
  __builtin_amdgcn_global_load_lds(                                           \
      (const __attribute__((address_space(1))) void*)(gp),                    \
      (__attribute__((address_space(3))) void*)(lp), 16, 0, 0)

// ---------------- f32->bf16 convert: branch-free, 4-deep ILP, nontemporal ---
__global__ void cvt_nt(const float* __restrict__ X, const float* __restrict__ Bm,
                       short* __restrict__ Xb, short* __restrict__ Bb) {
  const int b = blockIdx.x;
  const float* s;
  short* d;
  int base;
  if (b < 4096) { s = X;  d = Xb; base = b * 1024; }
  else          { s = Bm; d = Bb; base = (b - 4096) * 1024; }
  const int t = threadIdx.x;
  f32x4 v0 = __builtin_nontemporal_load((const f32x4*)(s + (size_t)(base +   0 + t) * 4));
  f32x4 v1 = __builtin_nontemporal_load((const f32x4*)(s + (size_t)(base + 256 + t) * 4));
  f32x4 v2 = __builtin_nontemporal_load((const f32x4*)(s + (size_t)(base + 512 + t) * 4));
  f32x4 v3 = __builtin_nontemporal_load((const f32x4*)(s + (size_t)(base + 768 + t) * 4));
#define STORE1(v_, off_) do {                                                 \
    s16x4 o;                                                                  \
    o[0] = f2bf(v_[0]); o[1] = f2bf(v_[1]);                                   \
    o[2] = f2bf(v_[2]); o[3] = f2bf(v_[3]);                                   \
    __builtin_nontemporal_store(o, (s16x4*)(d + (size_t)(base + (off_) + t) * 4)); \
  } while (0)
  STORE1(v0, 0);
  STORE1(v1, 256);
  STORE1(v2, 512);
  STORE1(v3, 768);
#undef STORE1
}

// ---------------- deep-pipelined 256^2 GEMM, 1 barrier/iter -----------------
// 8 waves (2Mx4N), per-wave 128x64 out. BK=32, 4-slot LDS ring (128 KiB).
// Iter j: compute K-tile j (slot j&3), stage K-tile j+3 (slot (j-1)&3).
// vmcnt(8) at iter end gates K-tile j+1 (its 4 loads are >=8 old).
// Mid-iter barriers removed: reads-vs-reads have no hazard; the write hazard
// (stage into slot (j-1)&3) is fenced by iter j-1's closing barrier.
__global__ __launch_bounds__(512, 2) void gemm8p3(
    const short* __restrict__ Xb, const short* __restrict__ Bb,
    float* __restrict__ U) {
  extern __shared__ __align__(16) short smem[];
  short* As = smem;             // 4 slots x 8192 shorts (64 KiB)
  short* Bs = smem + 4 * ASLOT; // 4 slots x 8192 shorts (64 KiB)

  // XCD-aware swizzle: nwg=256, each XCD gets a 4(tm) x 8(tn) rectangle
  const int wg  = blockIdx.x;
  const int swz = (wg & 7) * 32 + (wg >> 3);
  const int tm = swz >> 3;              // 0..31
  const int tn = swz & 7;               // 0..7
  const int row0 = tm * BM, col0 = tn * BN;

  const int tid  = threadIdx.x;
  const int lane = tid & 63;
  const int wid  = tid >> 6;
  const int wr = (wid >> 2) * 128;      // 2 m-groups
  const int wc = (wid & 3) * 64;        // 4 n-groups
  const int r16 = lane & 15;
  const int ks8 = (lane >> 4) * 8;      // 16B k-slice (shorts)

  // fragment read offsets (within slot): phys granule = ks ^ ((r>>1)&3)
  int offA[8], offB[4];
#pragma unroll
  for (int m = 0; m < 8; ++m) {
    const int r = wr + m * 16 + r16;
    offA[m] = r * BK + (ks8 ^ (((r >> 1) & 3) * 8));
  }
#pragma unroll
  for (int n = 0; n < 4; ++n) {
    const int r = wc + n * 16 + r16;
    offB[n] = r * BK + (ks8 ^ (((r >> 1) & 3) * 8));
  }

  // staging: LDS dest linear tid*16B; global source pre-swizzled
  const int srow = tid >> 2;            // 0..127
  const int sg   = (tid & 3) ^ ((tid >> 3) & 3);
  const short* gA0 = Xb + (size_t)(row0 + srow) * HDIM + sg * 8;
  const short* gA1 = gA0 + (size_t)128 * HDIM;
  const short* gB0 = Bb + (size_t)(col0 + srow) * HDIM + sg * 8;
  const short* gB1 = gB0 + (size_t)128 * HDIM;

  f32x4 acc[8][4] = {};

  // prologue: stage K-tiles 0,1,2 -> slots 0,1,2 (12 loads), wait K0, barrier
#pragma unroll
  for (int k = 0; k < 3; ++k) {
    GL(gA0 + k * BK, &As[k * ASLOT + tid * 8]);
    GL(gA1 + k * BK, &As[k * ASLOT + 4096 + tid * 8]);
    GL(gB0 + k * BK, &Bs[k * BSLOT + tid * 8]);
    GL(gB1 + k * BK, &Bs[k * BSLOT + 4096 + tid * 8]);
  }
  VMW(8);
  SB();

#define ITER(J_, ST_, VMA_, SBF_) do {                                        \
    const int sc_ = (J_) & 3;                                                 \
    const int si_ = ((J_) + 3) & 3;                                           \
    const int ko_ = ((J_) + 3) * BK;                                          \
    s16x8 af[4], bfv[4];                                                      \
    _Pragma("unroll") for (int m = 0; m < 4; ++m)                             \
      af[m] = *(const s16x8*)&As[sc_ * ASLOT + offA[m]];                      \
    _Pragma("unroll") for (int n = 0; n < 4; ++n)                             \
      bfv[n] = *(const s16x8*)&Bs[sc_ * BSLOT + offB[n]];                     \
    if (ST_) {                                                                \
      GL(gA0 + ko_, &As[si_ * ASLOT + tid * 8]);                              \
      GL(gA1 + ko_, &As[si_ * ASLOT + 4096 + tid * 8]);                       \
    }                                                                         \
    __builtin_amdgcn_s_setprio(1);                                            \
    _Pragma("unroll") for (int m = 0; m < 4; ++m)                             \
      _Pragma("unroll") for (int n = 0; n < 4; ++n)                           \
        acc[m][n] = __builtin_amdgcn_mfma_f32_16x16x32_bf16(                  \
            af[m], bfv[n], acc[m][n], 0, 0, 0);                               \
    __builtin_amdgcn_s_setprio(0);                                            \
    _Pragma("unroll") for (int m = 0; m < 4; ++m)                             \
      af[m] = *(const s16x8*)&As[sc_ * ASLOT + offA[4 + m]];                  \
    if (ST_) {                                                                \
      GL(gB0 + ko_, &Bs[si_ * BSLOT + tid * 8]);                              \
      GL(gB1 + ko_, &Bs[si_ * BSLOT + 4096 + tid * 8]);                       \
    }                                                                         \
    __builtin_amdgcn_s_setprio(1);                                            \
    _Pragma("unroll") for (int m = 0; m < 4; ++m)                             \
      _Pragma("unroll") for (int n = 0; n < 4; ++n)                           \
        acc[4 + m][n] = __builtin_amdgcn_mfma_f32_16x16x32_bf16(              \
            af[m], bfv[n], acc[4 + m][n], 0, 0, 0);                           \
    __builtin_amdgcn_s_setprio(0);                                            \
    VMA_;                                                                     \
    SBF_;                                                                     \
  } while (0)

#pragma unroll 4
  for (int j = 0; j < NT - 4; ++j) ITER(j, true, VMW(8), SB());
  ITER(NT - 4, true,  VMW(8), SB());   // stages K-tile NT-1
  ITER(NT - 3, false, VMW(4), SB());
  ITER(NT - 2, false, VMW(0), SB());
  ITER(NT - 1, false, (void)0, (void)0);
#undef ITER

  // epilogue: C/D mapping col=lane&15, row=(lane>>4)*4+j [verified R1-R10]
  const int crow = row0 + wr + ((lane >> 4) << 2);
  const int ccol = col0 + wc + r16;
#pragma unroll
  for (int m = 0; m < 8; ++m)
#pragma unroll
    for (int n = 0; n < 4; ++n)
#pragma unroll
      for (int j = 0; j < 4; ++j)
        U[(size_t)(crow + m * 16 + j) * HDIM + ccol + n * 16] = acc[m][n][j];
}

// ---------------- fallback GEMM (R1, f32 reg-staging, proven) ---------------
__global__ __launch_bounds__(256, 2) void gemm_f32_fb(
    const float* __restrict__ X, const float* __restrict__ Bm,
    float* __restrict__ U) {
#define LDK 40
#define FBM 128
#define FBK 32
#define FNT (HDIM / FBK)
  __shared__ __align__(16) short As[2][FBM * LDK];
  __shared__ __align__(16) short Bs[2][FBM * LDK];
  const int wg  = blockIdx.x;
  const int cpx = (TDIM / FBM) * (HDIM / FBM) / 8;
  const int swz = (wg & 7) * cpx + (wg >> 3);
  const int tm = swz >> 4;
  const int tn = swz & 15;
  const int row0 = tm * FBM, col0 = tn * FBM;
  const int tid  = threadIdx.x;
  const int lane = tid & 63;
  const int wid  = tid >> 6;
  const int wr = (wid >> 1) * 64;
  const int wc = (wid & 1) * 64;
  const int srow = tid >> 2;
  const int sk   = (tid & 3) << 3;
  const float* gA  = X  + (size_t)(row0 + srow) * HDIM + sk;
  const float* gA2 = gA + 64 * HDIM;
  const float* gB  = Bm + (size_t)(col0 + srow) * HDIM + sk;
  const float* gB2 = gB + 64 * HDIM;
  f32x4 a00, a01, a10, a11, b00, b01, b10, b11;
#define LOADREG(kt) do {                                                      \
    const float* p;                                                           \
    p = gA  + (kt) * FBK; a00 = *(const f32x4*)p; a01 = *(const f32x4*)(p+4); \
    p = gA2 + (kt) * FBK; a10 = *(const f32x4*)p; a11 = *(const f32x4*)(p+4); \
    p = gB  + (kt) * FBK; b00 = *(const f32x4*)p; b01 = *(const f32x4*)(p+4); \
    p = gB2 + (kt) * FBK; b10 = *(const f32x4*)p; b11 = *(const f32x4*)(p+4); \
  } while (0)
#define CVT8(v, lo, hi) do {                                                  \
    v[0] = f2bf(lo[0]); v[1] = f2bf(lo[1]); v[2] = f2bf(lo[2]);               \
    v[3] = f2bf(lo[3]); v[4] = f2bf(hi[0]); v[5] = f2bf(hi[1]);               \
    v[6] = f2bf(hi[2]); v[7] = f2bf(hi[3]);                                   \
  } while (0)
#define DSWRITE(buf) do {                                                     \
    s16x8 v;                                                                  \
    CVT8(v, a00, a01); *(s16x8*)&As[buf][srow * LDK + sk] = v;                \
    CVT8(v, a10, a11); *(s16x8*)&As[buf][(srow + 64) * LDK + sk] = v;         \
    CVT8(v, b00, b01); *(s16x8*)&Bs[buf][srow * LDK + sk] = v;                \
    CVT8(v, b10, b11); *(s16x8*)&Bs[buf][(srow + 64) * LDK + sk] = v;         \
  } while (0)
  f32x4 acc[4][4] = {};
#define COMPUTE(buf) do {                                                     \
    const int r16_ = lane & 15;                                               \
    const int ks_  = (lane >> 4) * 8;                                         \
    s16x8 af[4], bfr[4];                                                      \
    _Pragma("unroll") for (int m = 0; m < 4; ++m)                             \
      af[m] = *(const s16x8*)&As[buf][(wr + m * 16 + r16_) * LDK + ks_];      \
    _Pragma("unroll") for (int n = 0; n < 4; ++n)                             \
      bfr[n] = *(const s16x8*)&Bs[buf][(wc + n * 16 + r16_) * LDK + ks_];     \
    _Pragma("unroll") for (int m = 0; m < 4; ++m)                             \
      _Pragma("unroll") for (int n = 0; n < 4; ++n)                           \
        acc[m][n] = __builtin_amdgcn_mfma_f32_16x16x32_bf16(                  \
            af[m], bfr[n], acc[m][n], 0, 0, 0);                               \
  } while (0)
  LOADREG(0);
  DSWRITE(0);
  __syncthreads();
#pragma unroll 2
  for (int kt = 0; kt < FNT; ++kt) {
    const int cur = kt & 1;
    if (kt + 1 < FNT) LOADREG(kt + 1);
    COMPUTE(cur);
    if (kt + 1 < FNT) DSWRITE(cur ^ 1);
    __syncthreads();
  }
  const int crow = wr + ((lane >> 4) << 2);
  const int ccol = wc + (lane & 15);
#pragma unroll
  for (int m = 0; m < 4; ++m)
#pragma unroll
    for (int n = 0; n < 4; ++n)
#pragma unroll
      for (int j = 0; j < 4; ++j)
        U[(size_t)(row0 + crow + m * 16 + j) * HDIM + (col0 + ccol + n * 16)] =
            acc[m][n][j];
#undef LOADREG
#undef CVT8
#undef DSWRITE
#undef COMPUTE
#undef LDK
#undef FBM
#undef FBK
#undef FNT
}

// ---------------- scan pass 1: per-chunk local scan end values ---------------
__global__ void scan_pass1(const float* __restrict__ U,
                           const float* __restrict__ lam,
                           float* __restrict__ e) {
  const int c = (blockIdx.y * 256 + threadIdx.x) * 4;
  const int j = blockIdx.x;
  const f32x4 l4 = *(const f32x4*)&lam[c];
  f32x4 h = {0.f, 0.f, 0.f, 0.f};
  const float* up = U + (size_t)j * LCH * HDIM + c;
#pragma unroll 4
  for (int t = 0; t < LCH; ++t) {
    f32x4 u4 = *(const f32x4*)up;
    h = l4 * h + u4;
    up += HDIM;
  }
  *(f32x4*)&e[(size_t)j * HDIM + c] = h;
}

// ---------------- scan pass 2: carry scan over chunks (in-place on e) --------
__global__ void scan_carry(float* __restrict__ e, const float* __restrict__ lam) {
  const int c = (blockIdx.x * 256 + threadIdx.x) * 4;
  const f32x4 l4 = *(const f32x4*)&lam[c];
  f32x4 p = l4;
#pragma unroll
  for (int i = 0; i < 6; ++i) p = p * p;   // lam^64
  f32x4 E = {0.f, 0.f, 0.f, 0.f};
  for (int j = 0; j < GCH; ++j) {
    f32x4 ej = *(const f32x4*)&e[(size_t)j * HDIM + c];
    *(f32x4*)&e[(size_t)j * HDIM + c] = E;  // carry into chunk j = E_{j-1}
    E = p * E + ej;
  }
}

// ---------------- scan pass 3: final scan with carry, in-place U -> h --------
__global__ void scan_pass3(float* __restrict__ U, const float* __restrict__ lam,
                           const float* __restrict__ carry) {
  const int c = (blockIdx.y * 256 + threadIdx.x) * 4;
  const int j = blockIdx.x;
  const f32x4 l4 = *(const f32x4*)&lam[c];
  f32x4 h = *(const f32x4*)&carry[(size_t)j * HDIM + c];
  float* up = U + (size_t)j * LCH * HDIM + c;
#pragma unroll 4
  for (int t = 0; t < LCH; ++t) {
    f32x4 u4 = *(const f32x4*)up;
    h = l4 * h + u4;
    *(f32x4*)up = h;
    up += HDIM;
  }
}

extern "C" void kernel_launch(void* const* d_in, const int* in_sizes, int n_in,
                              void* d_out, int out_size, void* d_ws, size_t ws_size,
                              hipStream_t stream) {
  const float* X   = (const float*)d_in[0];
  const float* lam = (const float*)d_in[1];
  const float* Bm  = (const float*)d_in[2];
  float* U = (float*)d_out;              // u then h, in-place

  if (ws_size >= WS_NEED) {
    short* Xb = (short*)d_ws;
    short* Bb = (short*)((char*)d_ws + XBF_BYTES);
    float* e  = (float*)((char*)d_ws + XBF_BYTES + BBF_BYTES);

    hipFuncSetAttribute((const void*)gemm8p3,
                        hipFuncAttributeMaxDynamicSharedMemorySize, 131072);

    cvt_nt<<<dim3(5120), dim3(256), 0, stream>>>(X, Bm, Xb, Bb);
    gemm8p3<<<dim3((TDIM / BM) * (HDIM / BN)), dim3(512), 131072, stream>>>(
        Xb, Bb, U);
    scan_pass1<<<dim3(GCH, HDIM / 1024), dim3(256), 0, stream>>>(U, lam, e);
    scan_carry<<<dim3(HDIM / 1024), dim3(256), 0, stream>>>(e, lam);
    scan_pass3<<<dim3(GCH, HDIM / 1024), dim3(256), 0, stream>>>(U, lam, e);
  } else {
    float* e = (float*)d_ws;
    gemm_f32_fb<<<dim3((TDIM / 128) * (HDIM / 128)), dim3(256), 0, stream>>>(
        X, Bm, U);
    scan_pass1<<<dim3(GCH, HDIM / 1024), dim3(256), 0, stream>>>(U, lam, e);
    scan_carry<<<dim3(HDIM / 1024), dim3(256), 0, stream>>>(e, lam);
    scan_pass3<<<dim3(GCH, HDIM / 1024), dim3(256), 0, stream>>>(U, lam, e);
  }
}

// Round 12
// 109.609 us; speedup vs baseline: 1.2435x; 1.2435x over previous
//
#include <hip/hip_runtime.h>
#include <hip/hip_bf16.h>

// BPTT diagonal RNN: u = X @ B^T, h_t = lam*h_{t-1} + u_t (chunked scan).
// R12: R4 champion (fused f32-in GEMM, BK=64 XOR swizzle, 0 conflicts) with
// scan_pass1 FUSED into the GEMM epilogue (per-block chunk-scan ends computed
// from acc via Horner + shfl_xor reduce). Launches: gemm, carry, pass3.

#define TDIM 8192
#define HDIM 2048
#define BM 256
#define BN 256
#define KT 64                  // K per iter (floats)
#define NIT (HDIM / KT)        // 32 iters
#define SLOT 16384             // shorts per LDS slot (256 rows x 64 k)
#define LCH 64                 // scan chunk length
#define GCH (TDIM / LCH)       // 128 chunks

typedef float f32x4 __attribute__((ext_vector_type(4)));
typedef short s16x4 __attribute__((ext_vector_type(4)));
typedef short s16x8 __attribute__((ext_vector_type(8)));

static __device__ __forceinline__ short f2bf(float f) {
  __bf16 b = (__bf16)f;                 // RNE f32->bf16
  return __builtin_bit_cast(short, b);
}

// ---------------- fused GEMM + pass1 epilogue -------------------------------
// 8 waves (2Mx4N), per-wave out 128x64 (8m x 4n frags of 16x16).
// LDS rows = 64 shorts (128B) = 8 x 16B chunks; phys chunk = logical ^ (row&7)
// -> conflict-free ds_read_b128 frags AND conflict-free ds_write staging. [R4]
__global__ __launch_bounds__(512, 2) void gemm_fused2(
    const float* __restrict__ X, const float* __restrict__ Bm,
    const float* __restrict__ lam,
    float* __restrict__ U, float* __restrict__ e) {
  extern __shared__ __align__(16) short smem[];
  short* As = smem;              // 2 slots x 16384 shorts (64 KiB)
  short* Bs = smem + 2 * SLOT;   // 2 slots x 16384 shorts (64 KiB)

  // XCD-aware swizzle: nwg=256 (%8==0, bijective)
  const int wg  = blockIdx.x;
  const int swz = (wg & 7) * 32 + (wg >> 3);
  const int tm = swz >> 3;              // 0..31
  const int tn = swz & 7;               // 0..7
  const int row0 = tm * BM, col0 = tn * BN;

  const int tid  = threadIdx.x;
  const int lane = tid & 63;
  const int wid  = tid >> 6;
  const int wr = (wid >> 2) * 128;      // 2 m-groups
  const int wc = (wid & 3) * 64;        // 4 n-groups

  // fragment ds_read offsets (kh=0); kh=1 = offset ^ 32 shorts  [R4-verified]
  const int g4 = lane >> 4;
  int offA[8], offB[4];
#pragma unroll
  for (int m = 0; m < 8; ++m) {
    const int r = wr + m * 16 + (lane & 15);
    offA[m] = r * 64 + ((g4 ^ (r & 3)) << 3) + (((r >> 2) & 1) << 5);
  }
#pragma unroll
  for (int n = 0; n < 4; ++n) {
    const int r = wc + n * 16 + (lane & 15);
    offB[n] = r * 64 + ((g4 ^ (r & 3)) << 3) + (((r >> 2) & 1) << 5);
  }

  // staging: load c in 0..7: row = (tid>>4) + c*32, floats [(tid&15)*4, +4)
  const int lrow   = tid >> 4;          // 0..31
  const int lcol16 = (tid & 15) * 4;    // float col within tile k-window
  const float* gA = X  + (size_t)(row0 + lrow) * HDIM + lcol16;
  const float* gB = Bm + (size_t)(col0 + lrow) * HDIM + lcol16;

  // ds_write (b64) offsets: wrow=lrow+c*32, chunk=(tid&15)>>1, half=tid&1
  int offW[8];
#pragma unroll
  for (int c = 0; c < 8; ++c) {
    const int wrow = lrow + c * 32;
    offW[c] = wrow * 64 + ((((tid & 15) >> 1) ^ (wrow & 7)) << 3) + (tid & 1) * 4;
  }

#define ISSUE(dst, gp, t_) do {                                               \
    _Pragma("unroll") for (int c = 0; c < 8; ++c)                             \
      dst[c] = *(const f32x4*)((gp) + (size_t)c * 32 * HDIM + (t_) * KT);     \
  } while (0)

#define CVTWR(arr, base, sl) do {                                             \
    _Pragma("unroll") for (int c = 0; c < 8; ++c) {                           \
      s16x4 v;                                                                \
      v[0] = f2bf(arr[c][0]); v[1] = f2bf(arr[c][1]);                         \
      v[2] = f2bf(arr[c][2]); v[3] = f2bf(arr[c][3]);                         \
      *(s16x4*)&base[(sl) * SLOT + offW[c]] = v;                              \
    }                                                                         \
  } while (0)

#define PHASE(sl, khx) do {                                                   \
    s16x8 af[8], bfv[4];                                                      \
    _Pragma("unroll") for (int m = 0; m < 8; ++m)                             \
      af[m] = *(const s16x8*)&As[(sl) * SLOT + (offA[m] ^ (khx))];            \
    _Pragma("unroll") for (int n = 0; n < 4; ++n)                             \
      bfv[n] = *(const s16x8*)&Bs[(sl) * SLOT + (offB[n] ^ (khx))];           \
    __builtin_amdgcn_s_setprio(1);                                            \
    _Pragma("unroll") for (int m = 0; m < 8; ++m)                             \
      _Pragma("unroll") for (int n = 0; n < 4; ++n)                           \
        acc[m][n] = __builtin_amdgcn_mfma_f32_16x16x32_bf16(                  \
            af[m], bfv[n], acc[m][n], 0, 0, 0);                               \
    __builtin_amdgcn_s_setprio(0);                                            \
  } while (0)

  f32x4 acc[8][4] = {};
  f32x4 ra[8], rb[8];

  // prologue: tile 0 -> slot 0 (R4 schedule)
  ISSUE(ra, gA, 0);
  ISSUE(rb, gB, 0);
  CVTWR(ra, As, 0);
  CVTWR(rb, Bs, 0);
  __syncthreads();

  for (int j = 0; j < NIT - 1; ++j) {
    const int cur = j & 1;
    ISSUE(ra, gA, j + 1);               // A loads for next tile (early issue)
    PHASE(cur, 0);                      // kh=0: 12 ds_read + 32 MFMA
    CVTWR(ra, As, cur ^ 1);             // A aged ~1 MFMA phase
    ISSUE(rb, gB, j + 1);               // B loads (covered by phase 1)
    PHASE(cur, 32);                     // kh=1
    CVTWR(rb, Bs, cur ^ 1);
    __syncthreads();
  }
  {
    const int cur = (NIT - 1) & 1;
    PHASE(cur, 0);
    PHASE(cur, 32);
  }

  // ---------------- epilogue 1: write U (C/D map verified R1-R11) -----------
  const int crow = row0 + wr + (g4 << 2);
  const int ccol = col0 + wc + (lane & 15);
#pragma unroll
  for (int m = 0; m < 8; ++m)
#pragma unroll
    for (int n = 0; n < 4; ++n)
#pragma unroll
      for (int j = 0; j < 4; ++j)
        U[(size_t)(crow + m * 16 + j) * HDIM + ccol + n * 16] = acc[m][n][j];

  // ---------------- epilogue 2: fused scan_pass1 ----------------------------
  // Thread holds rows 16*(m&3) + 4*g4 + jj (in-chunk) for 2 chunks:
  // chunk local q = wr/64 + (m>=4).  e_j[c] = sum_r lam_c^(63-r) * u_r
  //  = lam^{4(3-g4)} * Horner_{mq}(lam^16, Horner_{jj}(lam, u)).
#pragma unroll
  for (int n = 0; n < 4; ++n) {
    const int c = ccol + n * 16;
    const float l  = lam[c];
    const float l2 = l * l;
    const float l4 = l2 * l2;
    const float l8 = l4 * l4;
    const float l16 = l8 * l8;
    // lam^{4*(3-g4)}
    float lg = 1.f;
    if (g4 < 3) lg = l4;
    if (g4 < 2) lg *= l4;
    if (g4 < 1) lg *= l4;
#pragma unroll
    for (int half = 0; half < 2; ++half) {      // m 0..3 / 4..7
      float S = 0.f;
#pragma unroll
      for (int mq = 0; mq < 4; ++mq) {
        const f32x4 a = acc[half * 4 + mq][n];
        const float T = ((a[0] * l + a[1]) * l + a[2]) * l + a[3];
        S = S * l16 + T;
      }
      S *= lg;
      // sum over the 4 g4-lanes (lane ^ 16, lane ^ 32)
      S += __shfl_xor(S, 16, 64);
      S += __shfl_xor(S, 32, 64);
      if (g4 == 0) {
        const int j = tm * 4 + (wr >> 6) + half;   // global chunk index
        e[(size_t)j * HDIM + c] = S;
      }
    }
  }

#undef ISSUE
#undef CVTWR
#undef PHASE
}

// ---------------- fallback GEMM (R1, f32 reg-staging, proven) ---------------
__global__ __launch_bounds__(256, 2) void gemm_f32_fb(
    const float* __restrict__ X, const float* __restrict__ Bm,
    float* __restrict__ U) {
#define LDK 40
#define FBM 128
#define FBK 32
#define FNT (HDIM / FBK)
  __shared__ __align__(16) short As[2][FBM * LDK];
  __shared__ __align__(16) short Bs[2][FBM * LDK];
  const int wg  = blockIdx.x;
  const int cpx = (TDIM / FBM) * (HDIM / FBM) / 8;
  const int swz = (wg & 7) * cpx + (wg >> 3);
  const int tm = swz >> 4;
  const int tn = swz & 15;
  const int row0 = tm * FBM, col0 = tn * FBM;
  const int tid  = threadIdx.x;
  const int lane = tid & 63;
  const int wid  = tid >> 6;
  const int wr = (wid >> 1) * 64;
  const int wc = (wid & 1) * 64;
  const int srow = tid >> 2;
  const int sk   = (tid & 3) << 3;
  const float* gA  = X  + (size_t)(row0 + srow) * HDIM + sk;
  const float* gA2 = gA + 64 * HDIM;
  const float* gB  = Bm + (size_t)(col0 + srow) * HDIM + sk;
  const float* gB2 = gB + 64 * HDIM;
  f32x4 a00, a01, a10, a11, b00, b01, b10, b11;
#define LOADREG(kt) do {                                                      \
    const float* p;                                                           \
    p = gA  + (kt) * FBK; a00 = *(const f32x4*)p; a01 = *(const f32x4*)(p+4); \
    p = gA2 + (kt) * FBK; a10 = *(const f32x4*)p; a11 = *(const f32x4*)(p+4); \
    p = gB  + (kt) * FBK; b00 = *(const f32x4*)p; b01 = *(const f32x4*)(p+4); \
    p = gB2 + (kt) * FBK; b10 = *(const f32x4*)p; b11 = *(const f32x4*)(p+4); \
  } while (0)
#define CVT8(v, lo, hi) do {                                                  \
    v[0] = f2bf(lo[0]); v[1] = f2bf(lo[1]); v[2] = f2bf(lo[2]);               \
    v[3] = f2bf(lo[3]); v[4] = f2bf(hi[0]); v[5] = f2bf(hi[1]);               \
    v[6] = f2bf(hi[2]); v[7] = f2bf(hi[3]);                                   \
  } while (0)
#define DSWRITE(buf) do {                                                     \
    s16x8 v;                                                                  \
    CVT8(v, a00, a01); *(s16x8*)&As[buf][srow * LDK + sk] = v;                \
    CVT8(v, a10, a11); *(s16x8*)&As[buf][(srow + 64) * LDK + sk] = v;         \
    CVT8(v, b00, b01); *(s16x8*)&Bs[buf][srow * LDK + sk] = v;                \
    CVT8(v, b10, b11); *(s16x8*)&Bs[buf][(srow + 64) * LDK + sk] = v;         \
  } while (0)
  f32x4 acc[4][4] = {};
#define COMPUTE(buf) do {                                                     \
    const int r16_ = lane & 15;                                               \
    const int ks_  = (lane >> 4) * 8;                                         \
    s16x8 af[4], bfr[4];                                                      \
    _Pragma("unroll") for (int m = 0; m < 4; ++m)                             \
      af[m] = *(const s16x8*)&As[buf][(wr + m * 16 + r16_) * LDK + ks_];      \
    _Pragma("unroll") for (int n = 0; n < 4; ++n)                             \
      bfr[n] = *(const s16x8*)&Bs[buf][(wc + n * 16 + r16_) * LDK + ks_];     \
    _Pragma("unroll") for (int m = 0; m < 4; ++m)                             \
      _Pragma("unroll") for (int n = 0; n < 4; ++n)                           \
        acc[m][n] = __builtin_amdgcn_mfma_f32_16x16x32_bf16(                  \
            af[m], bfr[n], acc[m][n], 0, 0, 0);                               \
  } while (0)
  LOADREG(0);
  DSWRITE(0);
  __syncthreads();
#pragma unroll 2
  for (int kt = 0; kt < FNT; ++kt) {
    const int cur = kt & 1;
    if (kt + 1 < FNT) LOADREG(kt + 1);
    COMPUTE(cur);
    if (kt + 1 < FNT) DSWRITE(cur ^ 1);
    __syncthreads();
  }
  const int crow = wr + ((lane >> 4) << 2);
  const int ccol = wc + (lane & 15);
#pragma unroll
  for (int m = 0; m < 4; ++m)
#pragma unroll
    for (int n = 0; n < 4; ++n)
#pragma unroll
      for (int j = 0; j < 4; ++j)
        U[(size_t)(row0 + crow + m * 16 + j) * HDIM + (col0 + ccol + n * 16)] =
            acc[m][n][j];
#undef LOADREG
#undef CVT8
#undef DSWRITE
#undef COMPUTE
#undef LDK
#undef FBM
#undef FBK
#undef FNT
}

// ---------------- scan pass 1 (fallback path only) ---------------------------
__global__ void scan_pass1(const float* __restrict__ U,
                           const float* __restrict__ lam,
                           float* __restrict__ e) {
  const int c = (blockIdx.y * 256 + threadIdx.x) * 4;
  const int j = blockIdx.x;
  const f32x4 l4 = *(const f32x4*)&lam[c];
  f32x4 h = {0.f, 0.f, 0.f, 0.f};
  const float* up = U + (size_t)j * LCH * HDIM + c;
#pragma unroll 4
  for (int t = 0; t < LCH; ++t) {
    f32x4 u4 = *(const f32x4*)up;
    h = l4 * h + u4;
    up += HDIM;
  }
  *(f32x4*)&e[(size_t)j * HDIM + c] = h;
}

// ---------------- scan pass 2: carry scan over chunks (in-place on e) --------
__global__ void scan_carry(float* __restrict__ e, const float* __restrict__ lam) {
  const int c = (blockIdx.x * 256 + threadIdx.x) * 4;
  const f32x4 l4 = *(const f32x4*)&lam[c];
  f32x4 p = l4;
#pragma unroll
  for (int i = 0; i < 6; ++i) p = p * p;   // lam^64
  f32x4 E = {0.f, 0.f, 0.f, 0.f};
  for (int j = 0; j < GCH; ++j) {
    f32x4 ej = *(const f32x4*)&e[(size_t)j * HDIM + c];
    *(f32x4*)&e[(size_t)j * HDIM + c] = E;  // carry into chunk j = E_{j-1}
    E = p * E + ej;
  }
}

// ---------------- scan pass 3: final scan with carry, in-place U -> h --------
__global__ void scan_pass3(float* __restrict__ U, const float* __restrict__ lam,
                           const float* __restrict__ carry) {
  const int c = (blockIdx.y * 256 + threadIdx.x) * 4;
  const int j = blockIdx.x;
  const f32x4 l4 = *(const f32x4*)&lam[c];
  f32x4 h = *(const f32x4*)&carry[(size_t)j * HDIM + c];
  float* up = U + (size_t)j * LCH * HDIM + c;
#pragma unroll 4
  for (int t = 0; t < LCH; ++t) {
    f32x4 u4 = *(const f32x4*)up;
    h = l4 * h + u4;
    *(f32x4*)up = h;
    up += HDIM;
  }
}

extern "C" void kernel_launch(void* const* d_in, const int* in_sizes, int n_in,
                              void* d_out, int out_size, void* d_ws, size_t ws_size,
                              hipStream_t stream) {
  const float* X   = (const float*)d_in[0];
  const float* lam = (const float*)d_in[1];
  const float* Bm  = (const float*)d_in[2];
  float* U = (float*)d_out;              // u then h, in-place
  float* e = (float*)d_ws;               // 1 MB chunk carries

  if (ws_size >= (size_t)GCH * HDIM * 4) {
    hipFuncSetAttribute((const void*)gemm_fused2,
                        hipFuncAttributeMaxDynamicSharedMemorySize, 131072);
    gemm_fused2<<<dim3((TDIM / BM) * (HDIM / BN)), dim3(512), 131072, stream>>>(
        X, Bm, lam, U, e);
    scan_carry<<<dim3(HDIM / 1024), dim3(256), 0, stream>>>(e, lam);
    scan_pass3<<<dim3(GCH, HDIM / 1024), dim3(256), 0, stream>>>(U, lam, e);
  } else {
    // (ws too small for e — cannot happen given prior rounds, but stay safe)
    gemm_f32_fb<<<dim3((TDIM / 128) * (HDIM / 128)), dim3(256), 0, stream>>>(
        X, Bm, U);
    scan_pass1<<<dim3(GCH, HDIM / 1024), dim3(256), 0, stream>>>(U, lam, e);
    scan_carry<<<dim3(HDIM / 1024), dim3(256), 0, stream>>>(e, lam);
    scan_pass3<<<dim3(GCH, HDIM / 1024), dim3(256), 0, stream>>>(U, lam, e);
  }
}